// Round 12
// baseline (391.991 us; speedup 1.0000x reference)
//
#include <hip/hip_runtime.h>

// ---------------------------------------------------------------------------
// STGCN forward, MI355X. Internal compute bf16-MFMA / fp32-accum.
// TC1 -> dense-L build (+L^T) -> L2=L*L (small gemm_bt) -> DUAL prop GEMM
// (P1=z*L^T, P2=z*(L^2)^T share the A tile) -> cheb combine -> TC2+stats
// -> BN finalize. T2 never materialized.
// All MFMA kernels: XOR slot-swizzle (pre-swizzled global src, swizzled read);
// runtime K-loops keep live sets under the 512-thread 128-VGPR cap (R9 lesson).
// ---------------------------------------------------------------------------

typedef __bf16 bf16;
typedef __bf16 bf16x8 __attribute__((ext_vector_type(8)));
typedef float  f32x4  __attribute__((ext_vector_type(4)));

__device__ __forceinline__ f32x4 mfma16(bf16x8 a, bf16x8 b, f32x4 c) {
  return __builtin_amdgcn_mfma_f32_16x16x32_bf16(a, b, c, 0, 0, 0);
}
__device__ __forceinline__ f32x4 splat4(float v) { f32x4 t = {v, v, v, v}; return t; }

// async global->LDS, 16B per lane; lds base must be wave-uniform (lane*16 auto)
__device__ __forceinline__ void lds_load16(const bf16* g, bf16* l) {
  __builtin_amdgcn_global_load_lds((const __attribute__((address_space(1))) void*)g,
                                   (__attribute__((address_space(3))) void*)l, 16, 0, 0);
}

#define NN 1024
#define EE 16384

// --------------------------- edge preprocessing ----------------------------
__global__ __launch_bounds__(256) void deg_kernel(const int* __restrict__ ei,
                                                  const float* __restrict__ ew,
                                                  float* __restrict__ deg) {
  int e = blockIdx.x * 256 + threadIdx.x;
  int r = ei[e], c = ei[EE + e];
  if (r != c) atomicAdd(&deg[r], ew[e]);
}

// L[col][row] += -dinv[row]*w*dinv[col]  (dense 1024x1024 fp32)
__global__ __launch_bounds__(256) void scatterL_kernel(const int* __restrict__ ei,
                                                       const float* __restrict__ ew,
                                                       const float* __restrict__ deg,
                                                       float* __restrict__ Lf) {
  int e = blockIdx.x * 256 + threadIdx.x;
  int r = ei[e], c = ei[EE + e];
  float w = (r == c) ? 0.0f : ew[e];
  float dr = deg[r], dc = deg[c];
  float ir = dr > 0.0f ? rsqrtf(dr) : 0.0f;
  float ic = dc > 0.0f ? rsqrtf(dc) : 0.0f;
  float norm = -(ir * w * ic);
  if (norm != 0.0f) atomicAdd(&Lf[(size_t)c * NN + r], norm);
}

// fp32 L -> bf16 Lbf AND bf16 LbfT (LDS-tiled transpose), 128x128 tiles
__global__ __launch_bounds__(256) void cvtLT_kernel(const float* __restrict__ Lf,
                                                    bf16* __restrict__ Lbf,
                                                    bf16* __restrict__ LbfT) {
  __shared__ bf16 T[128 * 136];                // pad 8 -> conflict-light
  const int bi = blockIdx.y, bj = blockIdx.x;  // tile (rows bi*128, cols bj*128)
  const int t = threadIdx.x;
  #pragma unroll
  for (int k = 0; k < 16; k++) {               // 16*256 float4 = 128x128
    int f4 = k * 256 + t;
    int r = f4 >> 5, c4 = f4 & 31;
    const float4 v = *(const float4*)(&Lf[(size_t)(bi * 128 + r) * NN + bj * 128 + c4 * 4]);
    bf16 b4[4] = {(bf16)v.x, (bf16)v.y, (bf16)v.z, (bf16)v.w};
    *(uint2*)(&Lbf[(size_t)(bi * 128 + r) * NN + bj * 128 + c4 * 4]) = *(uint2*)b4;
    #pragma unroll
    for (int q = 0; q < 4; q++) T[(c4 * 4 + q) * 136 + r] = b4[q];
  }
  __syncthreads();
  #pragma unroll
  for (int k = 0; k < 8; k++) {                // write transposed rows coalesced
    int idx = k * 256 + t;
    int rr = idx >> 4, cc = idx & 15;
    *(bf16x8*)(&LbfT[(size_t)(bj * 128 + rr) * NN + bi * 128 + cc * 8]) =
        *(const bf16x8*)(&T[rr * 136 + cc * 8]);
  }
}

// ------------------------------ weight prep --------------------------------
// Wc (fp32, 192x64): rows [0:64)=W0-W2, [64:128)=W1, [128:192)=2*W2
// W2c (bf16, [1152 cols][192 k]): col = og*48 + conv*16 + oo  (o = og*16+oo)
__global__ __launch_bounds__(256) void wprep_kernel(const float* __restrict__ W,
                                                    const float* __restrict__ w21,
                                                    const float* __restrict__ w22,
                                                    const float* __restrict__ w23,
                                                    float* __restrict__ Wc,
                                                    bf16* __restrict__ W2c) {
  int i = blockIdx.x * 256 + threadIdx.x;   // 912*256 = 233472 = 12288 + 221184 exact
  if (i < 12288) {
    int row = i >> 6, j = i & 63;
    int src = row >> 6, h = row & 63;
    float v;
    if (src == 0)      v = W[h * 64 + j] - W[2 * 4096 + h * 64 + j];
    else if (src == 1) v = W[4096 + h * 64 + j];
    else               v = 2.0f * W[2 * 4096 + h * 64 + j];
    Wc[i] = v;
  } else {
    int j2 = i - 12288;                      // [0, 221184)
    int c = j2 / 192, k = j2 % 192;
    int og = c / 48, r48 = c % 48;
    int conv = r48 >> 4, oo = r48 & 15;
    int o = og * 16 + oo;
    int kk = k >> 6, h = k & 63;
    const float* ws = (conv == 0) ? w21 : (conv == 1) ? w22 : w23;
    W2c[j2] = (bf16)ws[(o * 64 + h) * 3 + kk];
  }
}

// ------------------------------- TC1 ---------------------------------------
// zf[(b*10+t)*64+h][n] = relu(P*sigmoid(Q)+R), feature-major bf16
__global__ __launch_bounds__(256) void tc1_kernel(const float* __restrict__ X,
                                                  const float* __restrict__ w1, const float* __restrict__ c1,
                                                  const float* __restrict__ w2, const float* __restrict__ c2,
                                                  const float* __restrict__ w3, const float* __restrict__ c3,
                                                  bf16* __restrict__ zf) {
  int row = blockIdx.y;                       // (b*10+t)*64+h, [0,10240)
  int n = blockIdx.x * 256 + threadIdx.x;
  int h = row & 63, bt = row >> 6;
  int t = bt % 10, b = bt / 10;
  float P = c1[h], Q = c2[h], R = c3[h];
  const float* xb = X + (size_t)(b * 1024 + n) * 24;   // (B,N,C=2,T=12)
  #pragma unroll
  for (int c = 0; c < 2; c++)
    #pragma unroll
    for (int k = 0; k < 3; k++) {
      float xv = xb[c * 12 + t + k];
      int wi = (h * 2 + c) * 3 + k;
      P += xv * w1[wi]; Q += xv * w2[wi]; R += xv * w3[wi];
    }
  float Hv = P * (1.0f / (1.0f + __expf(-Q))) + R;
  Hv = Hv > 0.0f ? Hv : 0.0f;
  zf[(size_t)row * NN + n] = (bf16)Hv;
}

// --------------------------- B^T GEMM (bf16) -------------------------------
// C[M][Nc] = A[M][K] * Bt[Nc][K]^T ; 128x128 tile, BK=64, global_load_lds.
// Used for L2 = Lbf x LbfT (grid 8x8). XOR slot-swizzle.
__global__ __launch_bounds__(256) void gemm_bt(const bf16* __restrict__ A,
                                               const bf16* __restrict__ Bt,
                                               bf16* __restrict__ C,
                                               int M, int Nc, int K) {
  __shared__ __align__(16) bf16 As[8192];
  __shared__ __align__(16) bf16 Bs[8192];
  const int tid = threadIdx.x, lane = tid & 63, w = tid >> 6;
  const int wm = w >> 1, wn = w & 1;
  const int m0 = blockIdx.y * 128, n0 = blockIdx.x * 128;
  const int colL = lane & 15, kg = lane >> 4;
  const int rxor = colL & 7;

  f32x4 acc[4][4];
  #pragma unroll
  for (int i = 0; i < 4; i++)
    #pragma unroll
    for (int j = 0; j < 4; j++) acc[i][j] = splat4(0.0f);

  for (int kb = 0; kb < K; kb += 64) {
    if (kb) __syncthreads();
    #pragma unroll
    for (int i = 0; i < 4; i++) {
      int e = (w * 4 + i) * 512 + lane * 8;
      int row = e >> 6, s = (e >> 3) & 7;
      int ksw = ((s ^ (row & 7)) << 3);
      lds_load16(&A[(size_t)(m0 + row) * K + kb + ksw], &As[(w * 4 + i) * 512]);
      lds_load16(&Bt[(size_t)(n0 + row) * K + kb + ksw], &Bs[(w * 4 + i) * 512]);
    }
    __syncthreads();
    #pragma unroll
    for (int kk = 0; kk < 2; kk++) {
      bf16x8 af[4], bfr[4];
      #pragma unroll
      for (int mt = 0; mt < 4; mt++)
        af[mt] = *(const bf16x8*)(&As[(wm * 64 + mt * 16 + colL) * 64 +
                                      (((kk * 4 + kg) ^ rxor) << 3)]);
      #pragma unroll
      for (int nt = 0; nt < 4; nt++)
        bfr[nt] = *(const bf16x8*)(&Bs[(wn * 64 + nt * 16 + colL) * 64 +
                                       (((kk * 4 + kg) ^ rxor) << 3)]);
      #pragma unroll
      for (int mt = 0; mt < 4; mt++)
        #pragma unroll
        for (int nt = 0; nt < 4; nt++)
          acc[mt][nt] = mfma16(af[mt], bfr[nt], acc[mt][nt]);
    }
  }
  #pragma unroll
  for (int mt = 0; mt < 4; mt++)
    #pragma unroll
    for (int nt = 0; nt < 4; nt++) {
      int m = m0 + wm * 64 + mt * 16 + kg * 4;
      int n = n0 + wn * 64 + nt * 16 + colL;
      #pragma unroll
      for (int r = 0; r < 4; r++)
        C[(size_t)(m + r) * Nc + n] = (bf16)acc[mt][nt][r];
    }
}

// ----------------------- DUAL B^T GEMM (bf16) ------------------------------
// C1 = A*B1t^T, C2 = A*B2t^T sharing the A tile. 128x128 tiles, 8 waves:
// wave w -> output w>>2, quadrant (wm=(w>>1)&1, wn=w&1), acc[4][4]=64 VGPR.
// Halves barrier-phases & A traffic vs two sequential gemm_bt launches.
__global__ __launch_bounds__(512) void gemm_dual(const bf16* __restrict__ A,
                                                 const bf16* __restrict__ B1t,
                                                 const bf16* __restrict__ B2t,
                                                 bf16* __restrict__ C1,
                                                 bf16* __restrict__ C2,
                                                 int M, int Nc, int K) {
  __shared__ __align__(16) bf16 As[8192];
  __shared__ __align__(16) bf16 B1s[8192];
  __shared__ __align__(16) bf16 B2s[8192];
  const int tid = threadIdx.x, lane = tid & 63, w = tid >> 6;
  const int out = w >> 2, wm = (w >> 1) & 1, wn = w & 1;
  const int m0 = blockIdx.y * 128, n0 = blockIdx.x * 128;
  const int colL = lane & 15, kg = lane >> 4;
  const int rxor = colL & 7;

  f32x4 acc[4][4];
  #pragma unroll
  for (int i = 0; i < 4; i++)
    #pragma unroll
    for (int j = 0; j < 4; j++) acc[i][j] = splat4(0.0f);

  for (int kb = 0; kb < K; kb += 64) {
    if (kb) __syncthreads();
    #pragma unroll
    for (int i = 0; i < 2; i++) {            // 512 thr: 2 rounds per region
      int e = (w * 2 + i) * 512 + lane * 8;
      int row = e >> 6, s = (e >> 3) & 7;
      int ksw = ((s ^ (row & 7)) << 3);
      lds_load16(&A[(size_t)(m0 + row) * K + kb + ksw], &As[(w * 2 + i) * 512]);
      lds_load16(&B1t[(size_t)(n0 + row) * K + kb + ksw], &B1s[(w * 2 + i) * 512]);
      lds_load16(&B2t[(size_t)(n0 + row) * K + kb + ksw], &B2s[(w * 2 + i) * 512]);
    }
    __syncthreads();
    const bf16* Bs = out ? B2s : B1s;        // wave-uniform
    #pragma unroll
    for (int kk = 0; kk < 2; kk++) {
      bf16x8 af[4], bfr[4];
      #pragma unroll
      for (int mt = 0; mt < 4; mt++)
        af[mt] = *(const bf16x8*)(&As[(wm * 64 + mt * 16 + colL) * 64 +
                                      (((kk * 4 + kg) ^ rxor) << 3)]);
      #pragma unroll
      for (int nt = 0; nt < 4; nt++)
        bfr[nt] = *(const bf16x8*)(&Bs[(wn * 64 + nt * 16 + colL) * 64 +
                                       (((kk * 4 + kg) ^ rxor) << 3)]);
      #pragma unroll
      for (int mt = 0; mt < 4; mt++)
        #pragma unroll
        for (int nt = 0; nt < 4; nt++)
          acc[mt][nt] = mfma16(af[mt], bfr[nt], acc[mt][nt]);
    }
  }
  bf16* C = out ? C2 : C1;
  #pragma unroll
  for (int mt = 0; mt < 4; mt++)
    #pragma unroll
    for (int nt = 0; nt < 4; nt++) {
      int m = m0 + wm * 64 + mt * 16 + kg * 4;
      int n = n0 + wn * 64 + nt * 16 + colL;
      #pragma unroll
      for (int r = 0; r < 4; r++)
        C[(size_t)(m + r) * Nc + n] = (bf16)acc[mt][nt][r];
    }
}

// ------------------------- cheb combine (vector) ---------------------------
// Tg[n][b][t][j] = relu(cheb_b[j] + sum_h z*Wc[0:64] + P1*Wc[64:128] + P2*Wc[128:192])
__global__ __launch_bounds__(256) void combine_kernel(const bf16* __restrict__ zf,
                                                      const bf16* __restrict__ P1f,
                                                      const bf16* __restrict__ P2f,
                                                      const float* __restrict__ Wc,
                                                      const float* __restrict__ chebb,
                                                      bf16* __restrict__ Tg) {
  const int slab = blockIdx.y;                 // bt in [0,160)
  const int b = slab / 10, t = slab % 10;
  const int lane = threadIdx.x & 63;
  const int jg = __builtin_amdgcn_readfirstlane(threadIdx.x >> 6);  // wave-uniform
  const int n = blockIdx.x * 64 + lane;

  float acc[16];
  #pragma unroll
  for (int j = 0; j < 16; j++) acc[j] = chebb[jg * 16 + j];

  const size_t zoff = (size_t)(slab * 64) * NN + n;
  #pragma unroll 1
  for (int src = 0; src < 3; src++) {
    const bf16* Z = (src == 0) ? zf : (src == 1) ? P1f : P2f;
    const float* wsrc = Wc + (size_t)(src * 64) * 64 + jg * 16;
    #pragma unroll 4
    for (int h = 0; h < 64; h++) {
      float v = (float)Z[zoff + (size_t)h * NN];
      const float* wr = wsrc + h * 64;         // uniform -> s_load
      #pragma unroll
      for (int j = 0; j < 16; j++) acc[j] += v * wr[j];
    }
  }

  bf16 tmp[16];
  #pragma unroll
  for (int j = 0; j < 16; j++) {
    float x = acc[j];
    tmp[j] = (bf16)(x > 0.0f ? x : 0.0f);
  }
  size_t base = (size_t)((n * 16 + b) * 10 + t) * 64 + jg * 16;
  *(bf16x8*)(&Tg[base])     = *(const bf16x8*)(&tmp[0]);
  *(bf16x8*)(&Tg[base + 8]) = *(const bf16x8*)(&tmp[8]);
}

// ----------------------- TC2 as GEMM + fused BN stats ----------------------
// (R11-verified: VGPR 88, no spill, 103 us.) 12 runtime passes of 96 cols.
__global__ __launch_bounds__(512) void tc2_kernel(const bf16* __restrict__ Tg,
                                                  const bf16* __restrict__ W2c,
                                                  const float* __restrict__ b1,
                                                  const float* __restrict__ b2,
                                                  const float* __restrict__ b3,
                                                  float* __restrict__ nsum,
                                                  float* __restrict__ nsq,
                                                  bf16* __restrict__ slice) {
  __shared__ __align__(16) char smem[122880];  // A 96K + 2 x W 12K
  bf16* Asm = (bf16*)smem;
  const int rb = blockIdx.x;                   // 512 blocks: b(16) x tpp(8) x nch(4)
  const int b = rb >> 5, tpp = (rb >> 2) & 7, n0 = (rb & 3) << 8;
  const int tid = threadIdx.x, lane = tid & 63, w = tid >> 6;
  const int wm = w >> 1, wn = w & 1;
  const int colL = lane & 15, kg = lane >> 4;
  const int rxor = colL & 7;

  #pragma unroll
  for (int i = 0; i < 12; i++) {
    int fb = w * 12288 + i * 1024 + lane * 16;
    int row = fb / 384;
    int s = (fb % 384) >> 4;
    int koff = (s & ~7) * 8 + (((s & 7) ^ (row & 7)) << 3);
    lds_load16(&Tg[(size_t)((n0 + row) * 16 + b) * 640 + tpp * 64 + koff],
               (bf16*)(smem + w * 12288 + i * 1024));
  }
  auto stageW = [&](int colBase, int ks, int buf) {
    {
      int lc = w * 8 + (lane >> 3);
      int cg = colBase + lc;
      int ksrc = ks * 64 + (((lane & 7) ^ (cg & 7)) << 3);
      lds_load16(&W2c[(size_t)cg * 192 + ksrc],
                 (bf16*)(smem + 98304 + buf * 12288 + w * 1024));
    }
    if (w < 4) {
      int s2 = w + 8;
      int lc = s2 * 8 + (lane >> 3);
      int cg = colBase + lc;
      int ksrc = ks * 64 + (((lane & 7) ^ (cg & 7)) << 3);
      lds_load16(&W2c[(size_t)cg * 192 + ksrc],
                 (bf16*)(smem + 98304 + buf * 12288 + s2 * 1024));
    }
  };
  stageW(0, 0, 0);
  __syncthreads();

  float ssum[4][4], ssq[4][4];
  #pragma unroll
  for (int mt = 0; mt < 4; mt++)
    #pragma unroll
    for (int r = 0; r < 4; r++) { ssum[mt][r] = 0.0f; ssq[mt][r] = 0.0f; }

  #pragma unroll 1
  for (int pass = 0; pass < 12; pass++) {
    const int colBase = pass * 96;
    const int pb = pass & 1;

    f32x4 acc[4][3];
    #pragma unroll
    for (int i = 0; i < 4; i++)
      #pragma unroll
      for (int j = 0; j < 3; j++) acc[i][j] = splat4(0.0f);

    #pragma unroll
    for (int ks = 0; ks < 3; ks++) {
      const int bufCur = pb ^ (ks & 1);
      if (pass < 11 || ks < 2) {
        if (ks < 2) stageW(colBase, ks + 1, bufCur ^ 1);
        else        stageW(colBase + 96, 0, bufCur ^ 1);
      }
      const bf16* Wsb = (const bf16*)(smem + 98304 + bufCur * 12288);
      #pragma unroll
      for (int kk = 0; kk < 2; kk++) {
        bf16x8 af[4], bfr[3];
        #pragma unroll
        for (int mt = 0; mt < 4; mt++)
          af[mt] = *(const bf16x8*)(&Asm[(wm * 64 + mt * 16 + colL) * 192 + ks * 64 +
                                         (((kk * 4 + kg) ^ rxor) << 3)]);
        #pragma unroll
        for (int j = 0; j < 3; j++)
          bfr[j] = *(const bf16x8*)(&Wsb[(wn * 48 + j * 16 + colL) * 64 +
                                         (((kk * 4 + kg) ^ rxor) << 3)]);
        #pragma unroll
        for (int mt = 0; mt < 4; mt++)
          #pragma unroll
          for (int j = 0; j < 3; j++)
            acc[mt][j] = mfma16(af[mt], bfr[j], acc[mt][j]);
      }
      __syncthreads();
    }

    const int o = ((pass * 2 + wn) << 4) + colL;
    const float bv1 = b1[o], bv2 = b2[o], bv3 = b3[o];
    #pragma unroll
    for (int mt = 0; mt < 4; mt++)
      #pragma unroll
      for (int r = 0; r < 4; r++) {
        float pv = acc[mt][0][r] + bv1;
        float qv = acc[mt][1][r] + bv2;
        float rv = acc[mt][2][r] + bv3;
        float h = pv * (1.0f / (1.0f + __expf(-qv))) + rv;
        h = h > 0.0f ? h : 0.0f;
        ssum[mt][r] += h;
        ssq[mt][r] += h * h;
        if (tpp == 7) {
          int n = n0 + wm * 64 + mt * 16 + kg * 4 + r;
          slice[(size_t)((b << 10) + n) * 384 + o] = (bf16)h;
        }
      }
  }

  float* sred = (float*)smem;
  sred[tid] = 0.0f;
  __syncthreads();
  #pragma unroll
  for (int mt = 0; mt < 4; mt++)
    #pragma unroll
    for (int r = 0; r < 4; r++) {
      float s = ssum[mt][r], q = ssq[mt][r];
      #pragma unroll
      for (int d = 1; d < 16; d <<= 1) {
        s += __shfl_xor(s, d);
        q += __shfl_xor(q, d);
      }
      if (colL == 0) {
        int rl = wm * 64 + mt * 16 + kg * 4 + r;
        atomicAdd(&sred[rl * 2], s);
        atomicAdd(&sred[rl * 2 + 1], q);
      }
    }
  __syncthreads();
  if (tid < 256) {
    atomicAdd(&nsum[n0 + tid], sred[tid * 2]);
    atomicAdd(&nsq[n0 + tid], sred[tid * 2 + 1]);
  }
}

// ----------------------------- BN finalize ---------------------------------
__global__ __launch_bounds__(256) void bnstat_kernel(const float* __restrict__ nsum,
                                                     const float* __restrict__ nsq,
                                                     const float* __restrict__ gamma,
                                                     const float* __restrict__ beta,
                                                     float* __restrict__ scoff) {
  int n = blockIdx.x * 256 + threadIdx.x;       // 1024 exact
  const float inv_cnt = 1.0f / 49152.0f;        // B*8*384
  float m = nsum[n] * inv_cnt;
  float var = nsq[n] * inv_cnt - m * m;
  float sc = rsqrtf(var + 1e-5f) * gamma[n];
  scoff[n] = sc;
  scoff[1024 + n] = beta[n] - m * sc;
}

// out[f], f = c*16384 + b*1024 + n  (== reshape(T,B,N,OUT) flat order)
__global__ __launch_bounds__(256) void final_kernel(const bf16* __restrict__ slice,
                                                    const float* __restrict__ scoff,
                                                    float* __restrict__ out) {
  int f = blockIdx.x * 256 + threadIdx.x;       // 6291456 exact
  int c = f >> 14, rem = f & 16383;
  int b = rem >> 10, n = rem & 1023;
  out[f] = (float)slice[(size_t)((b << 10) + n) * 384 + c] * scoff[n] + scoff[1024 + n];
}

// ---------------------------------------------------------------------------
extern "C" void kernel_launch(void* const* d_in, const int* in_sizes, int n_in,
                              void* d_out, int out_size, void* d_ws, size_t ws_size,
                              hipStream_t stream) {
  const float* X    = (const float*)d_in[0];
  const int*   ei   = (const int*)d_in[1];
  const float* ew   = (const float*)d_in[2];
  const float* t1w1 = (const float*)d_in[3];
  const float* t1b1 = (const float*)d_in[4];
  const float* t1w2 = (const float*)d_in[5];
  const float* t1b2 = (const float*)d_in[6];
  const float* t1w3 = (const float*)d_in[7];
  const float* t1b3 = (const float*)d_in[8];
  const float* chebW = (const float*)d_in[9];
  const float* chebB = (const float*)d_in[10];
  const float* t2w1 = (const float*)d_in[11];
  const float* t2b1 = (const float*)d_in[12];
  const float* t2w2 = (const float*)d_in[13];
  const float* t2b2 = (const float*)d_in[14];
  const float* t2w3 = (const float*)d_in[15];
  const float* t2b3 = (const float*)d_in[16];
  const float* gamma = (const float*)d_in[17];
  const float* beta  = (const float*)d_in[18];
  float* out = (float*)d_out;

  char* ws = (char*)d_ws;
  float* Lf    = (float*)(ws);                  // 4 MB dense L (fp32 scatter target)
  float* deg   = (float*)(ws + 4194304);
  float* nsum  = (float*)(ws + 4198400);
  float* nsq   = (float*)(ws + 4202496);
  bf16*  Lbf   = (bf16*)(ws + 4210688);         // 2 MB
  bf16*  zf    = (bf16*)(ws + 6307840);         // 20 MB feature-major z
  bf16*  P1f   = (bf16*)(ws + 27279360);        // 20 MB
  bf16*  P2f   = (bf16*)(ws + 48250880);        // 20 MB
  bf16*  Tg    = (bf16*)(ws + 69222400);        // 20 MB node-major
  float* Wc    = (float*)(ws + 90193920);       // 48 KB combined cheb weights
  bf16*  W2c   = (bf16*)(ws + 90243072);        // 432 KB tc2 weights [col][k]
  bf16*  slice = (bf16*)(ws + 90685440);        // 12 MB t''=7 slice
  float* scoff = (float*)(ws + 103268352);      // 8 KB
  bf16*  LbfT  = (bf16*)(ws + 103276544);       // 2 MB transposed L
  bf16*  L2bf  = (bf16*)(ws + 105373696);       // 2 MB L^2 (ends 107.5 MB)

  hipMemsetAsync(ws, 0, 4206592, stream);       // Lf + deg + nsum + nsq

  wprep_kernel<<<912, 256, 0, stream>>>(chebW, t2w1, t2w2, t2w3, Wc, W2c);
  tc1_kernel<<<dim3(4, 10240), 256, 0, stream>>>(X, t1w1, t1b1, t1w2, t1b2, t1w3, t1b3, zf);
  deg_kernel<<<64, 256, 0, stream>>>(ei, ew, deg);
  scatterL_kernel<<<64, 256, 0, stream>>>(ei, ew, deg, Lf);
  cvtLT_kernel<<<dim3(8, 8), 256, 0, stream>>>(Lf, Lbf, LbfT);
  // L2 = L * L  (C[i][j] = sum_k Lbf[i][k] * LbfT[j][k] = sum_k L[i][k]*L[k][j])
  gemm_bt<<<dim3(8, 8), 256, 0, stream>>>(Lbf, LbfT, L2bf, 1024, 1024, 1024);
  // P1 = z*L^T and P2 = z*(L^2)^T in one pass over z
  gemm_dual<<<dim3(8, 80), 512, 0, stream>>>(zf, Lbf, L2bf, P1f, P2f, 10240, 1024, 1024);
  combine_kernel<<<dim3(16, 160), 256, 0, stream>>>(zf, P1f, P2f, Wc, chebB, Tg);
  tc2_kernel<<<512, 512, 0, stream>>>(Tg, W2c, t2b1, t2b2, t2b3, nsum, nsq, slice);
  bnstat_kernel<<<4, 256, 0, stream>>>(nsum, nsq, gamma, beta, scoff);
  final_kernel<<<24576, 256, 0, stream>>>(slice, scoff, out);
}